// Round 4
// baseline (813.382 us; speedup 1.0000x reference)
//
#include <hip/hip_runtime.h>
#include <math.h>

// Problem constants: B=1, L=512, C_S=384, H=12, D=32
// ws layout (floats):
//   q_ws    : 512*384            = 196608
//   kv_ws   : 512*768            = 393216
//   o_ws    : 512*384            = 196608
//   bias_ws : 12*512*512         = 3145728   [h][i][j]  (bias, then attn in-place)
//   gate_ws : 12*512*512         = 3145728   [h][i][j]  (already sigmoid'ed)
//   wcat_ws : 24*384             = 9216      [h][k] transposed Wb|Wg
// total = 7087104 floats = 28.35 MB

typedef float vf4 __attribute__((ext_vector_type(4)));   // native vec for nontemporal builtins

// ---------------------------------------------------------------------------
// Generic small SGEMM: C[M x N] = A[M x K] @ B[K x N] + bias (row-major).
// Tile 32(M) x 64(N), K-chunk 32, 256 threads, 2x4 micro-tile.
// ---------------------------------------------------------------------------
__global__ __launch_bounds__(256) void sgemm_bias(const float* __restrict__ A, int lda,
                                                  const float* __restrict__ B, int ldb,
                                                  const float* __restrict__ bias,
                                                  float* __restrict__ C, int ldc, int K)
{
    __shared__ float As[32 * 36];   // [k][m]
    __shared__ float Bs[32 * 68];   // [k][n]

    const int t  = threadIdx.x;
    const int m0 = blockIdx.y * 32;
    const int n0 = blockIdx.x * 64;
    const int tx = t & 15;
    const int ty = t >> 4;

    float acc[2][4];
    #pragma unroll
    for (int i = 0; i < 2; ++i)
        #pragma unroll
        for (int j = 0; j < 4; ++j) acc[i][j] = 0.f;

    for (int kc = 0; kc < K; kc += 32) {
        __syncthreads();
        {
            int r = t >> 3, c = (t & 7) * 4;
            float4 av = *(const float4*)&A[(size_t)(m0 + r) * lda + kc + c];
            As[(c + 0) * 36 + r] = av.x;
            As[(c + 1) * 36 + r] = av.y;
            As[(c + 2) * 36 + r] = av.z;
            As[(c + 3) * 36 + r] = av.w;
        }
        #pragma unroll
        for (int i = 0; i < 2; ++i) {
            int slot = i * 256 + t;
            int r = slot >> 4, c = (slot & 15) * 4;
            *(float4*)&Bs[r * 68 + c] = *(const float4*)&B[(size_t)(kc + r) * ldb + n0 + c];
        }
        __syncthreads();
        #pragma unroll 8
        for (int k = 0; k < 32; ++k) {
            float2 a = *(const float2*)&As[k * 36 + ty * 2];
            float4 b = *(const float4*)&Bs[k * 68 + tx * 4];
            acc[0][0] = fmaf(a.x, b.x, acc[0][0]);
            acc[0][1] = fmaf(a.x, b.y, acc[0][1]);
            acc[0][2] = fmaf(a.x, b.z, acc[0][2]);
            acc[0][3] = fmaf(a.x, b.w, acc[0][3]);
            acc[1][0] = fmaf(a.y, b.x, acc[1][0]);
            acc[1][1] = fmaf(a.y, b.y, acc[1][1]);
            acc[1][2] = fmaf(a.y, b.z, acc[1][2]);
            acc[1][3] = fmaf(a.y, b.w, acc[1][3]);
        }
    }

    float4 bv = *(const float4*)&bias[n0 + tx * 4];
    #pragma unroll
    for (int im = 0; im < 2; ++im) {
        float4 r;
        r.x = acc[im][0] + bv.x;
        r.y = acc[im][1] + bv.y;
        r.z = acc[im][2] + bv.z;
        r.w = acc[im][3] + bv.w;
        *(float4*)&C[(size_t)(m0 + ty * 2 + im) * ldc + n0 + tx * 4] = r;
    }
}

// ---------------------------------------------------------------------------
// Tiny prep: wcat[h][k] = (h<12 ? Wb[k][h] : Wg[k][h-12])
// ---------------------------------------------------------------------------
__global__ __launch_bounds__(256) void wcat_kernel(const float* __restrict__ Wb,
                                                   const float* __restrict__ Wg,
                                                   float* __restrict__ wcat)
{
    int idx = blockIdx.x * 256 + threadIdx.x;
    if (idx < 24 * 384) {
        int hh = idx / 384, k = idx % 384;
        wcat[idx] = (hh < 12) ? Wb[k * 12 + hh] : Wg[k * 12 + (hh - 12)];
    }
}

// ---------------------------------------------------------------------------
// bias/gate streaming kernel v3: the 402 MB z read.
// One thread per (i,j) pair. Explicit register double-buffer: chunk c+1's
// full 128 B line (8 x float4, nontemporal) is issued BEFORE chunk c's
// compute, so HBM latency hides under 768 FMAs. __launch_bounds__(256,2)
// gives the allocator a 256-VGPR budget so cur/nxt (64 VGPRs) stay live —
// round 2's VGPR=36 dribble is the failure this fixes.
// W loads are wave-uniform -> scalarized to s_load.
// ---------------------------------------------------------------------------
__global__ __launch_bounds__(256, 2) void biasgate_kernel(const float* __restrict__ z,
                                                          const float* __restrict__ wcat,
                                                          const float* __restrict__ bb,
                                                          const float* __restrict__ bg,
                                                          float* __restrict__ bias_out,
                                                          float* __restrict__ gate_out)
{
    const int t = threadIdx.x;
    const size_t p = (size_t)blockIdx.x * 256 + t;
    const float* zp = z + p * 384;

    float acc[24];
    #pragma unroll
    for (int h = 0; h < 24; ++h) acc[h] = 0.f;

    vf4 cur[8], nxt[8];
    #pragma unroll
    for (int i = 0; i < 8; ++i)
        cur[i] = __builtin_nontemporal_load((const vf4*)&zp[i * 4]);

    #pragma unroll 1
    for (int c = 0; c < 12; ++c) {
        if (c < 11) {
            const int kn = (c + 1) * 32;
            #pragma unroll
            for (int i = 0; i < 8; ++i)
                nxt[i] = __builtin_nontemporal_load((const vf4*)&zp[kn + i * 4]);
        }
        const int kc = c * 32;
        #pragma unroll
        for (int k4 = 0; k4 < 8; ++k4) {
            const vf4 zv = cur[k4];
            const float* wp = wcat + kc + k4 * 4;
            #pragma unroll
            for (int hh = 0; hh < 24; ++hh) {
                float4 w = *(const float4*)&wp[hh * 384];   // wave-uniform -> s_load
                acc[hh] = fmaf(zv.x, w.x,
                          fmaf(zv.y, w.y,
                          fmaf(zv.z, w.z,
                          fmaf(zv.w, w.w, acc[hh]))));
            }
        }
        #pragma unroll
        for (int i = 0; i < 8; ++i) cur[i] = nxt[i];
    }

    #pragma unroll
    for (int hh = 0; hh < 12; ++hh)
        bias_out[(size_t)hh * 262144 + p] = acc[hh] + bb[hh];
    #pragma unroll
    for (int hh = 0; hh < 12; ++hh) {
        float x = acc[12 + hh] + bg[hh];
        gate_out[(size_t)hh * 262144 + p] = 1.f / (1.f + expf(-x));
    }
}

// ---------------------------------------------------------------------------
// attn_sm: logits = qk/sqrt(D) + bias, mask, softmax, * gate.
// Block = (h, 8 query rows). Thread (r = t>>5, l = t&31) owns row i0+r,
// columns j = m*32+l (16 of them) held in REGISTERS — no score LDS at all.
// Row softmax via width-32 shuffles. Writes attn in-place over bias_ws.
// ---------------------------------------------------------------------------
__global__ __launch_bounds__(256) void attn_sm(const float* __restrict__ q_ws,
                                               const float* __restrict__ kv_ws,
                                               float* __restrict__ attn_ws,   // = bias_ws
                                               const float* __restrict__ gate_ws,
                                               const int* __restrict__ mask)
{
    __shared__ float ql[8 * 32];
    __shared__ int   mi[8];

    const int t  = threadIdx.x;
    const int h  = blockIdx.y;
    const int i0 = blockIdx.x * 8;
    const int r  = t >> 5;
    const int l  = t & 31;

    ql[t] = q_ws[(size_t)(i0 + r) * 384 + h * 32 + l];
    if (t < 8) mi[t] = mask[i0 + t];
    __syncthreads();

    const float inv = 0.17677669529663687f;   // 1/sqrt(32)
    const size_t rowbase = ((size_t)h << 18) + (size_t)(i0 + r) * 512;
    const int mrow = mi[r];

    float lg[16];
    float mx = -3.0e38f;
    #pragma unroll
    for (int m = 0; m < 16; ++m) {
        const int j = m * 32 + l;
        const float* kp = kv_ws + (size_t)j * 768 + h * 32;
        float dot = 0.f;
        #pragma unroll
        for (int x = 0; x < 8; ++x) {
            float4 kr = *(const float4*)&kp[x * 4];
            float4 qv = *(const float4*)&ql[r * 32 + x * 4];   // broadcast
            dot = fmaf(kr.x, qv.x, dot);
            dot = fmaf(kr.y, qv.y, dot);
            dot = fmaf(kr.z, qv.z, dot);
            dot = fmaf(kr.w, qv.w, dot);
        }
        float bv = attn_ws[rowbase + j];                // bias (read before overwrite)
        float lgv = fmaf(dot, inv, bv);
        lg[m] = (mrow != 0 && mask[j] != 0) ? lgv : -1e9f;
        mx = fmaxf(mx, lg[m]);
    }
    #pragma unroll
    for (int off = 16; off >= 1; off >>= 1) mx = fmaxf(mx, __shfl_xor(mx, off, 32));

    float sum = 0.f;
    #pragma unroll
    for (int m = 0; m < 16; ++m) {
        lg[m] = expf(lg[m] - mx);
        sum += lg[m];
    }
    #pragma unroll
    for (int off = 16; off >= 1; off >>= 1) sum += __shfl_xor(sum, off, 32);
    const float isum = 1.f / sum;

    #pragma unroll
    for (int m = 0; m < 16; ++m) {
        const int j = m * 32 + l;
        float gt = gate_ws[rowbase + j];
        attn_ws[rowbase + j] = lg[m] * isum * gt;
    }
}

// ---------------------------------------------------------------------------
// attn_pv: o[h] = attn_h [512x512] @ v_h [512x32].
// Block = (h, 16 rows). Thread (ig = t>>5 -> rows ig, ig+8; d = t&31).
// K-chunks of 128 j staged in LDS: al (attn rows, broadcast reads) and
// vl (v rows, stride 36, conflict-free d-consecutive reads).
// ---------------------------------------------------------------------------
__global__ __launch_bounds__(256) void attn_pv(const float* __restrict__ attn_ws,
                                               const float* __restrict__ kv_ws,
                                               float* __restrict__ o_ws)
{
    __shared__ float al[16 * 128];   // [row][j]
    __shared__ float vl[128 * 36];   // [j][d]

    const int t  = threadIdx.x;
    const int h  = blockIdx.y;
    const int i0 = blockIdx.x * 16;
    const int d  = t & 31;
    const int ig = t >> 5;

    float acc0 = 0.f, acc1 = 0.f;

    for (int jc = 0; jc < 4; ++jc) {
        const int j0 = jc * 128;
        __syncthreads();
        // stage attn tile 16x128 (512 float4, 2/thread, coalesced)
        #pragma unroll
        for (int i = 0; i < 2; ++i) {
            int slot = i * 256 + t;
            int row = slot >> 5, c4 = slot & 31;
            *(float4*)&al[row * 128 + c4 * 4] =
                *(const float4*)&attn_ws[((size_t)h << 18) + (size_t)(i0 + row) * 512 + j0 + c4 * 4];
        }
        // stage v tile 128x32 (1024 float4, 4/thread)
        #pragma unroll
        for (int i = 0; i < 4; ++i) {
            int slot = i * 256 + t;
            int row = slot >> 3, c4 = slot & 7;
            *(float4*)&vl[row * 36 + c4 * 4] =
                *(const float4*)&kv_ws[(size_t)(j0 + row) * 768 + 384 + h * 32 + c4 * 4];
        }
        __syncthreads();
        #pragma unroll 8
        for (int j4 = 0; j4 < 32; ++j4) {
            float4 a0 = *(const float4*)&al[ig * 128 + j4 * 4];        // broadcast
            float4 a1 = *(const float4*)&al[(ig + 8) * 128 + j4 * 4];  // broadcast
            float v0 = vl[(j4 * 4 + 0) * 36 + d];
            float v1 = vl[(j4 * 4 + 1) * 36 + d];
            float v2 = vl[(j4 * 4 + 2) * 36 + d];
            float v3 = vl[(j4 * 4 + 3) * 36 + d];
            acc0 = fmaf(a0.x, v0, fmaf(a0.y, v1, fmaf(a0.z, v2, fmaf(a0.w, v3, acc0))));
            acc1 = fmaf(a1.x, v0, fmaf(a1.y, v1, fmaf(a1.z, v2, fmaf(a1.w, v3, acc1))));
        }
    }

    o_ws[(size_t)(i0 + ig) * 384 + h * 32 + d]     = acc0;
    o_ws[(size_t)(i0 + ig + 8) * 384 + h * 32 + d] = acc1;
}

// ---------------------------------------------------------------------------
extern "C" void kernel_launch(void* const* d_in, const int* in_sizes, int n_in,
                              void* d_out, int out_size, void* d_ws, size_t ws_size,
                              hipStream_t stream)
{
    const float* s    = (const float*)d_in[0];
    const float* z    = (const float*)d_in[1];
    const int*   mask = (const int*)  d_in[2];
    const float* Wq   = (const float*)d_in[3];
    const float* bq   = (const float*)d_in[4];
    const float* Wkv  = (const float*)d_in[5];
    const float* bkv  = (const float*)d_in[6];
    const float* Wb   = (const float*)d_in[7];
    const float* bb   = (const float*)d_in[8];
    const float* Wg   = (const float*)d_in[9];
    const float* bg   = (const float*)d_in[10];
    const float* Wout = (const float*)d_in[11];
    const float* bout = (const float*)d_in[12];
    float* out = (float*)d_out;

    float* ws      = (float*)d_ws;
    float* q_ws    = ws;                          // 512*384
    float* kv_ws   = q_ws + 512 * 384;            // 512*768
    float* o_ws    = kv_ws + 512 * 768;           // 512*384
    float* bias_ws = o_ws + 512 * 384;            // 12*512*512 (bias -> attn in-place)
    float* gate_ws = bias_ws + 12 * 512 * 512;    // 12*512*512
    float* wcat_ws = gate_ws + 12 * 512 * 512;    // 24*384

    // W transpose prep (tiny)
    wcat_kernel<<<36, 256, 0, stream>>>(Wb, Wg, wcat_ws);
    // q = s @ Wq + bq
    sgemm_bias<<<dim3(384 / 64, 512 / 32), 256, 0, stream>>>(s, 384, Wq, 384, bq, q_ws, 384, 384);
    // kv = s @ Wkv + bkv
    sgemm_bias<<<dim3(768 / 64, 512 / 32), 256, 0, stream>>>(s, 384, Wkv, 768, bkv, kv_ws, 768, 384);
    // bias/gate = z @ [Wb|Wg]    (the 402 MB stream)
    biasgate_kernel<<<1024, 256, 0, stream>>>(z, wcat_ws, bb, bg, bias_ws, gate_ws);
    // softmax(logits+bias, mask) * gate   (in-place over bias_ws)
    attn_sm<<<dim3(512 / 8, 12), 256, 0, stream>>>(q_ws, kv_ws, bias_ws, gate_ws, mask);
    // o = attn @ v
    attn_pv<<<dim3(512 / 16, 12), 256, 0, stream>>>(bias_ws, kv_ws, o_ws);
    // out = o @ Wout + bout
    sgemm_bias<<<dim3(384 / 64, 512 / 32), 256, 0, stream>>>(o_ws, 384, Wout, 384, bout, out, 384, 384);
}

// Round 5
// 769.181 us; speedup vs baseline: 1.0575x; 1.0575x over previous
//
#include <hip/hip_runtime.h>
#include <math.h>

// Problem constants: B=1, L=512, C_S=384, H=12, D=32
// ws layout (floats):
//   q_ws    : 512*384            = 196608
//   kv_ws   : 512*768            = 393216
//   o_ws    : 512*384            = 196608
//   bias_ws : 12*512*512         = 3145728   [h][i][j]
//   gate_ws : 12*512*512         = 3145728   [h][i][j] (already sigmoid'ed)
//   wcat_ws : 24*384             = 9216      [h][k] transposed Wb|Wg
// total = 7087104 floats = 28.35 MB

typedef float vf4 __attribute__((ext_vector_type(4)));
typedef __attribute__((address_space(3))) void       lds_vp;
typedef __attribute__((address_space(1))) const void gm_vp;

// ---------------------------------------------------------------------------
// Generic small SGEMM: C[M x N] = A[M x K] @ B[K x N] + bias (row-major).
// Tile 32(M) x 64(N), K-chunk 32, 256 threads, 2x4 micro-tile.
// ---------------------------------------------------------------------------
__global__ __launch_bounds__(256) void sgemm_bias(const float* __restrict__ A, int lda,
                                                  const float* __restrict__ B, int ldb,
                                                  const float* __restrict__ bias,
                                                  float* __restrict__ C, int ldc, int K)
{
    __shared__ float As[32 * 36];   // [k][m]
    __shared__ float Bs[32 * 68];   // [k][n]

    const int t  = threadIdx.x;
    const int m0 = blockIdx.y * 32;
    const int n0 = blockIdx.x * 64;
    const int tx = t & 15;
    const int ty = t >> 4;

    float acc[2][4];
    #pragma unroll
    for (int i = 0; i < 2; ++i)
        #pragma unroll
        for (int j = 0; j < 4; ++j) acc[i][j] = 0.f;

    for (int kc = 0; kc < K; kc += 32) {
        __syncthreads();
        {
            int r = t >> 3, c = (t & 7) * 4;
            float4 av = *(const float4*)&A[(size_t)(m0 + r) * lda + kc + c];
            As[(c + 0) * 36 + r] = av.x;
            As[(c + 1) * 36 + r] = av.y;
            As[(c + 2) * 36 + r] = av.z;
            As[(c + 3) * 36 + r] = av.w;
        }
        #pragma unroll
        for (int i = 0; i < 2; ++i) {
            int slot = i * 256 + t;
            int r = slot >> 4, c = (slot & 15) * 4;
            *(float4*)&Bs[r * 68 + c] = *(const float4*)&B[(size_t)(kc + r) * ldb + n0 + c];
        }
        __syncthreads();
        #pragma unroll 8
        for (int k = 0; k < 32; ++k) {
            float2 a = *(const float2*)&As[k * 36 + ty * 2];
            float4 b = *(const float4*)&Bs[k * 68 + tx * 4];
            acc[0][0] = fmaf(a.x, b.x, acc[0][0]);
            acc[0][1] = fmaf(a.x, b.y, acc[0][1]);
            acc[0][2] = fmaf(a.x, b.z, acc[0][2]);
            acc[0][3] = fmaf(a.x, b.w, acc[0][3]);
            acc[1][0] = fmaf(a.y, b.x, acc[1][0]);
            acc[1][1] = fmaf(a.y, b.y, acc[1][1]);
            acc[1][2] = fmaf(a.y, b.z, acc[1][2]);
            acc[1][3] = fmaf(a.y, b.w, acc[1][3]);
        }
    }

    float4 bv = *(const float4*)&bias[n0 + tx * 4];
    #pragma unroll
    for (int im = 0; im < 2; ++im) {
        float4 r;
        r.x = acc[im][0] + bv.x;
        r.y = acc[im][1] + bv.y;
        r.z = acc[im][2] + bv.z;
        r.w = acc[im][3] + bv.w;
        *(float4*)&C[(size_t)(m0 + ty * 2 + im) * ldc + n0 + tx * 4] = r;
    }
}

// ---------------------------------------------------------------------------
// Tiny prep: wcat[h][k] = (h<12 ? Wb[k][h] : Wg[k][h-12])
// ---------------------------------------------------------------------------
__global__ __launch_bounds__(256) void wcat_kernel(const float* __restrict__ Wb,
                                                   const float* __restrict__ Wg,
                                                   float* __restrict__ wcat)
{
    int idx = blockIdx.x * 256 + threadIdx.x;
    if (idx < 24 * 384) {
        int hh = idx / 384, k = idx % 384;
        wcat[idx] = (hh < 12) ? Wb[k * 12 + hh] : Wg[k * 12 + (hh - 12)];
    }
}

// ---------------------------------------------------------------------------
// bias/gate streaming kernel v4: the 402 MB z read, m97-pattern.
// Double-buffered LDS (2 x 256 rows x 32 k = 2 x 32 KB) filled by async
// global_load_lds width=16 (no VGPR round-trip -> the allocator can't
// dribble it; rounds 2 & 4 failed on exactly that). Per chunk: issue 8
// loads for chunk c+1, compute 768 FMAs on chunk c from LDS, then
// __syncthreads() whose vmcnt(0) drain lands AFTER compute — the loads
// get the whole compute phase to fly.
// LDS layout is unpadded row*32+col (lane-contiguous order required by
// global_load_lds); the 4-way read conflict costs ~150 cyc vs 1536 FMA
// cyc per chunk — irrelevant.
// W reads are wave-uniform from wcat -> s_load (scalar cache).
// ---------------------------------------------------------------------------
__global__ __launch_bounds__(256) void biasgate_kernel(const float* __restrict__ z,
                                                       const float* __restrict__ wcat,
                                                       const float* __restrict__ bb,
                                                       const float* __restrict__ bg,
                                                       float* __restrict__ bias_out,
                                                       float* __restrict__ gate_out)
{
    __shared__ float zt[2][256 * 32];   // 64 KB total

    const int t  = threadIdx.x;
    const size_t p0 = (size_t)blockIdx.x * 256;
    const size_t p  = p0 + t;

    // staging decomposition: wave wv, instr i covers rows wv*64+i*8 .. +8
    const int wv   = t >> 6;
    const int lane = t & 63;
    const int lrow = lane >> 3;        // 0..7
    const int lcol = (lane & 7) * 4;   // float offset 0,4,..,28

    float acc[24];
    #pragma unroll
    for (int h = 0; h < 24; ++h) acc[h] = 0.f;

    // prefetch chunk 0 into buffer 0
    #pragma unroll
    for (int i = 0; i < 8; ++i) {
        const int row = wv * 64 + i * 8 + lrow;
        __builtin_amdgcn_global_load_lds(
            (gm_vp*)(z + (p0 + row) * 384 + lcol),
            (lds_vp*)(&zt[0][row * 32 + lcol]), 16, 0, 0);
    }
    __syncthreads();   // vmcnt(0) drain: buffer 0 resident

    #pragma unroll 1
    for (int c = 0; c < 12; ++c) {
        const int cur = c & 1;
        // issue next chunk's async loads into the other buffer
        if (c < 11) {
            const int nk = (c + 1) * 32;
            #pragma unroll
            for (int i = 0; i < 8; ++i) {
                const int row = wv * 64 + i * 8 + lrow;
                __builtin_amdgcn_global_load_lds(
                    (gm_vp*)(z + (p0 + row) * 384 + nk + lcol),
                    (lds_vp*)(&zt[cur ^ 1][row * 32 + lcol]), 16, 0, 0);
            }
        }
        // compute on current buffer (resident since last barrier)
        const int kc = c * 32;
        #pragma unroll
        for (int k4 = 0; k4 < 8; ++k4) {
            const vf4 zv = *(const vf4*)&zt[cur][t * 32 + k4 * 4];
            const float* wp = wcat + kc + k4 * 4;
            #pragma unroll
            for (int hh = 0; hh < 24; ++hh) {
                float4 w = *(const float4*)&wp[hh * 384];   // wave-uniform -> s_load
                acc[hh] = fmaf(zv.x, w.x,
                          fmaf(zv.y, w.y,
                          fmaf(zv.z, w.z,
                          fmaf(zv.w, w.w, acc[hh]))));
            }
        }
        __syncthreads();   // drains next-chunk loads (overlapped) + syncs buffer swap
    }

    #pragma unroll
    for (int hh = 0; hh < 12; ++hh)
        bias_out[(size_t)hh * 262144 + p] = acc[hh] + bb[hh];
    #pragma unroll
    for (int hh = 0; hh < 12; ++hh) {
        float x = acc[12 + hh] + bg[hh];
        gate_out[(size_t)hh * 262144 + p] = 1.f / (1.f + expf(-x));
    }
}

// ---------------------------------------------------------------------------
// Attention (R2 known-good): block = (h, 16 query rows). Full 16x512 logits
// tile in LDS. A: logits  B: softmax*gate  C: o = attn @ v.
// ---------------------------------------------------------------------------
__global__ __launch_bounds__(256) void attn_kernel(const float* __restrict__ q_ws,
                                                   const float* __restrict__ kv_ws,
                                                   const float* __restrict__ bias_ws,
                                                   const float* __restrict__ gate_ws,
                                                   const int* __restrict__ mask,
                                                   float* __restrict__ o_ws)
{
    __shared__ float ql[16 * 36];
    __shared__ float kl[128 * 36];
    __shared__ float att[16 * 516];   // row stride 516 (pad 4)
    __shared__ int   mint[16];

    const int t  = threadIdx.x;
    const int h  = blockIdx.y;
    const int i0 = blockIdx.x * 16;

    for (int idx = t; idx < 512; idx += 256) {
        int ii = idx >> 5, d = idx & 31;
        ql[ii * 36 + d] = q_ws[(size_t)(i0 + ii) * 384 + h * 32 + d];
    }
    if (t < 16) mint[t] = mask[i0 + t];

    const float inv = 0.17677669529663687f;   // 1/sqrt(32)
    const int jl = t & 127;
    const int ip = t >> 7;                     // 0 or 1

    // Phase A: logits
    for (int jc = 0; jc < 4; ++jc) {
        const int j0 = jc * 128;
        __syncthreads();
        for (int idx = t; idx < 4096; idx += 256) {
            int jj = idx >> 5, d = idx & 31;
            kl[jj * 36 + d] = kv_ws[(size_t)(j0 + jj) * 768 + h * 32 + d];
        }
        __syncthreads();
        float4 kr[8];
        #pragma unroll
        for (int x = 0; x < 8; ++x) kr[x] = *(const float4*)&kl[jl * 36 + x * 4];
        const int mj = mask[j0 + jl];
        #pragma unroll
        for (int rr = 0; rr < 8; ++rr) {
            int ii = ip + rr * 2;
            float dot = 0.f;
            #pragma unroll
            for (int x = 0; x < 8; ++x) {
                float4 qv = *(const float4*)&ql[ii * 36 + x * 4];
                dot = fmaf(kr[x].x, qv.x, dot);
                dot = fmaf(kr[x].y, qv.y, dot);
                dot = fmaf(kr[x].z, qv.z, dot);
                dot = fmaf(kr[x].w, qv.w, dot);
            }
            float bv = bias_ws[((size_t)h << 18) + (size_t)(i0 + ii) * 512 + j0 + jl];
            float lg = fmaf(dot, inv, bv);
            att[ii * 516 + j0 + jl] = (mint[ii] != 0 && mj != 0) ? lg : -1e9f;
        }
    }
    __syncthreads();

    // Phase B: softmax * gate (row = t/16, 16 lanes per row, 32 elems each)
    {
        const int rr = t >> 4, g = t & 15;
        const int base = rr * 516 + g;
        float mx = -3.0e38f;
        #pragma unroll
        for (int n = 0; n < 32; ++n) mx = fmaxf(mx, att[base + n * 16]);
        #pragma unroll
        for (int off = 8; off >= 1; off >>= 1) mx = fmaxf(mx, __shfl_xor(mx, off));
        float sum = 0.f;
        #pragma unroll
        for (int n = 0; n < 32; ++n) {
            float e = expf(att[base + n * 16] - mx);
            att[base + n * 16] = e;
            sum += e;
        }
        #pragma unroll
        for (int off = 8; off >= 1; off >>= 1) sum += __shfl_xor(sum, off);
        float isum = 1.f / sum;
        const size_t gbase = ((size_t)h << 18) + (size_t)(i0 + rr) * 512 + g;
        #pragma unroll
        for (int n = 0; n < 32; ++n) {
            float gt = gate_ws[gbase + n * 16];
            att[base + n * 16] *= isum * gt;
        }
    }
    __syncthreads();

    // Phase C: o = attn @ v. thread = (group g = rows {g, g+8}, d)
    {
        const int d = t & 31, grp = t >> 5;
        const float* vp = kv_ws + 384 + h * 32 + d;
        float a0 = 0.f, a1 = 0.f;
        #pragma unroll 8
        for (int j = 0; j < 512; ++j) {
            float vv = vp[(size_t)j * 768];
            a0 = fmaf(att[grp * 516 + j], vv, a0);
            a1 = fmaf(att[(grp + 8) * 516 + j], vv, a1);
        }
        o_ws[(size_t)(i0 + grp) * 384 + h * 32 + d]     = a0;
        o_ws[(size_t)(i0 + grp + 8) * 384 + h * 32 + d] = a1;
    }
}

// ---------------------------------------------------------------------------
extern "C" void kernel_launch(void* const* d_in, const int* in_sizes, int n_in,
                              void* d_out, int out_size, void* d_ws, size_t ws_size,
                              hipStream_t stream)
{
    const float* s    = (const float*)d_in[0];
    const float* z    = (const float*)d_in[1];
    const int*   mask = (const int*)  d_in[2];
    const float* Wq   = (const float*)d_in[3];
    const float* bq   = (const float*)d_in[4];
    const float* Wkv  = (const float*)d_in[5];
    const float* bkv  = (const float*)d_in[6];
    const float* Wb   = (const float*)d_in[7];
    const float* bb   = (const float*)d_in[8];
    const float* Wg   = (const float*)d_in[9];
    const float* bg   = (const float*)d_in[10];
    const float* Wout = (const float*)d_in[11];
    const float* bout = (const float*)d_in[12];
    float* out = (float*)d_out;

    float* ws      = (float*)d_ws;
    float* q_ws    = ws;                          // 512*384
    float* kv_ws   = q_ws + 512 * 384;            // 512*768
    float* o_ws    = kv_ws + 512 * 768;           // 512*384
    float* bias_ws = o_ws + 512 * 384;            // 12*512*512
    float* gate_ws = bias_ws + 12 * 512 * 512;    // 12*512*512
    float* wcat_ws = gate_ws + 12 * 512 * 512;    // 24*384

    // W transpose prep (tiny)
    wcat_kernel<<<36, 256, 0, stream>>>(Wb, Wg, wcat_ws);
    // q = s @ Wq + bq
    sgemm_bias<<<dim3(384 / 64, 512 / 32), 256, 0, stream>>>(s, 384, Wq, 384, bq, q_ws, 384, 384);
    // kv = s @ Wkv + bkv
    sgemm_bias<<<dim3(768 / 64, 512 / 32), 256, 0, stream>>>(s, 384, Wkv, 768, bkv, kv_ws, 768, 384);
    // bias/gate = z @ [Wb|Wg]    (the 402 MB stream)
    biasgate_kernel<<<1024, 256, 0, stream>>>(z, wcat_ws, bb, bg, bias_ws, gate_ws);
    // softmax(qk/sqrt(D) + bias, mask) * gate, then @ v
    attn_kernel<<<dim3(512 / 16, 12), 256, 0, stream>>>(q_ws, kv_ws, bias_ws, gate_ws, mask, o_ws);
    // out = o @ Wout + bout
    sgemm_bias<<<dim3(384 / 64, 512 / 32), 256, 0, stream>>>(o_ws, 384, Wout, 384, bout, out, 384, 384);
}